// Round 1
// baseline (96.758 us; speedup 1.0000x reference)
//
#include <hip/hip_runtime.h>
#include <hip/hip_bf16.h>

// APELoss: F fg logits vs M bg logits pairwise + F x F fg part.
// d = (b - f) * LAMB; mask = b > f + TH (TH = -1).  rel_bg is implied by mask
// (p_min <= fg[i], monotone rounding) so no min pass is needed.
// Work in log2 domain: dl = (b-f)*LAMB*log2e.
//   u = 2^(-|dl|); lg = log2(1+u)
//   sigmoid(d)      = 2^(min(dl,0) - lg)
//   softplus(d)/ln2 = max(dl,0) + lg        (scale by ln2 once at the end)

#define APE_LAMB 4.0f
#define APE_KC   5.770780163555856f   // LAMB * log2(e); mask: dl > -APE_KC
#define APE_LN2  0.6931471805599453f

#if __has_builtin(__builtin_amdgcn_exp2f)
#define EXP2F(x) __builtin_amdgcn_exp2f(x)
#else
#define EXP2F(x) exp2f(x)
#endif
#if __has_builtin(__builtin_amdgcn_logf)
#define LOG2F(x) __builtin_amdgcn_logf(x)
#else
#define LOG2F(x) log2f(x)
#endif

constexpr int S_CHUNKS = 7;   // bg split; M=150528 = 7 * 21504 (21504 % 4 == 0)
constexpr int ROWS_A   = 8;   // fg rows per block in bg kernel
constexpr int ROWS_B   = 4;   // fg rows per block in fg-fg kernel
constexpr int TPB      = 256;

// ---------------- bg kernel: fp/dist/count contributions from bg pairs ------
__global__ __launch_bounds__(TPB) void ape_bg_kernel(
    const float* __restrict__ logits, int F, int M, int chunkLen,
    float* __restrict__ distA, float* __restrict__ rankA, float* __restrict__ cntA)
{
    const int rg  = blockIdx.x;
    const int s   = blockIdx.y;
    const int tid = threadIdx.x;
    const float* bg = logits + F;
    const int i0 = rg * ROWS_A;

    float fgl[ROWS_A];
#pragma unroll
    for (int r = 0; r < ROWS_A; ++r) {
        int i = i0 + r;
        fgl[r] = (i < F) ? logits[i] * APE_KC : __builtin_inff();  // inf -> zero contrib
    }

    float dist[ROWS_A], rank[ROWS_A], cnt[ROWS_A];
#pragma unroll
    for (int r = 0; r < ROWS_A; ++r) { dist[r] = 0.f; rank[r] = 0.f; cnt[r] = 0.f; }

    const int start = s * chunkLen;
    const int end   = min(start + chunkLen, M);

    for (int j = start + tid * 4; j < end; j += TPB * 4) {
        float v[4];
        if (j + 4 <= end) {
            float4 q = *reinterpret_cast<const float4*>(bg + j);
            v[0] = q.x; v[1] = q.y; v[2] = q.z; v[3] = q.w;
        } else {
#pragma unroll
            for (int k = 0; k < 4; ++k)
                v[k] = (j + k < end) ? bg[j + k] : -__builtin_inff();  // -inf -> zero contrib
        }
#pragma unroll
        for (int k = 0; k < 4; ++k) {
            float bgl = v[k] * APE_KC;
#pragma unroll
            for (int r = 0; r < ROWS_A; ++r) {
                float dl  = bgl - fgl[r];
                float u   = EXP2F(-fabsf(dl));
                float o   = 1.0f + u;
                float lg  = LOG2F(o);
                float sig = EXP2F(fminf(dl, 0.0f) - lg);
                float spl = fmaxf(dl, 0.0f) + lg;
                float m   = (dl > -APE_KC) ? 1.0f : 0.0f;
                cnt[r]  += m;
                rank[r] += m * sig;
                dist[r] += m * spl;
            }
        }
    }

    // block reduce: 256 threads -> one value per (row, quantity)
    __shared__ float red[4][ROWS_A * 3];
    const int lane = tid & 63, wid = tid >> 6;
#pragma unroll
    for (int r = 0; r < ROWS_A; ++r) {
        float d = dist[r], rk = rank[r], c = cnt[r];
        for (int off = 32; off > 0; off >>= 1) {
            d  += __shfl_down(d, off);
            rk += __shfl_down(rk, off);
            c  += __shfl_down(c, off);
        }
        if (lane == 0) { red[wid][r*3+0] = d; red[wid][r*3+1] = rk; red[wid][r*3+2] = c; }
    }
    __syncthreads();
    if (tid < ROWS_A * 3) {
        float sum = red[0][tid] + red[1][tid] + red[2][tid] + red[3][tid];
        int r = tid / 3, q = tid % 3;
        int i = i0 + r;
        if (i < F) {
            int idx = s * F + i;
            if      (q == 0) distA[idx] = sum;
            else if (q == 1) rankA[idx] = sum;
            else             cntA[idx]  = sum;
        }
    }
}

// ---------------- fg-fg kernel: pos/tp contributions ------------------------
__global__ __launch_bounds__(TPB) void ape_fg_kernel(
    const float* __restrict__ logits, const float* __restrict__ ious, int F,
    float* __restrict__ dist2, float* __restrict__ rank2, float* __restrict__ cnt2)
{
    const int i0  = blockIdx.x * ROWS_B;
    const int tid = threadIdx.x;

    float fgl[ROWS_B], ioui[ROWS_B];
#pragma unroll
    for (int r = 0; r < ROWS_B; ++r) {
        int i = i0 + r;
        fgl[r]  = (i < F) ? logits[i] * APE_KC : __builtin_inff();
        ioui[r] = (i < F) ? ious[i] : 0.f;
    }

    float dist[ROWS_B], rank[ROWS_B], cnt[ROWS_B];
#pragma unroll
    for (int r = 0; r < ROWS_B; ++r) { dist[r] = 0.f; rank[r] = 0.f; cnt[r] = 0.f; }

    for (int j = tid; j < F; j += TPB) {
        float fjl  = logits[j] * APE_KC;
        float iouj = ious[j];
#pragma unroll
        for (int r = 0; r < ROWS_B; ++r) {
            float dl  = fjl - fgl[r];
            float u   = EXP2F(-fabsf(dl));
            float o   = 1.0f + u;
            float lg  = LOG2F(o);
            float sig = EXP2F(fminf(dl, 0.0f) - lg);
            float spl = fmaxf(dl, 0.0f) + lg;
            bool above = dl > -APE_KC;                    // fg[j] > fg[i] + TH
            float ma = above ? 1.0f : 0.0f;               // pos|tp -> rank
            float mp = (above && (iouj < ioui[r])) ? 1.0f : 0.0f;  // pos -> dist,count
            rank[r] += ma * sig;
            dist[r] += mp * spl;
            cnt[r]  += mp;
        }
    }

    __shared__ float red[4][ROWS_B * 3];
    const int lane = tid & 63, wid = tid >> 6;
#pragma unroll
    for (int r = 0; r < ROWS_B; ++r) {
        float d = dist[r], rk = rank[r], c = cnt[r];
        for (int off = 32; off > 0; off >>= 1) {
            d  += __shfl_down(d, off);
            rk += __shfl_down(rk, off);
            c  += __shfl_down(c, off);
        }
        if (lane == 0) { red[wid][r*3+0] = d; red[wid][r*3+1] = rk; red[wid][r*3+2] = c; }
    }
    __syncthreads();
    if (tid < ROWS_B * 3) {
        float sum = red[0][tid] + red[1][tid] + red[2][tid] + red[3][tid];
        int r = tid / 3, q = tid % 3;
        int i = i0 + r;
        if (i < F) {
            if      (q == 0) dist2[i] = sum;
            else if (q == 1) rank2[i] = sum;
            else             cnt2[i]  = sum;
        }
    }
}

// ---------------- final: combine partials, per-row loss, scalar out ---------
__global__ __launch_bounds__(TPB) void ape_final_kernel(
    const float* __restrict__ ious, int F, int S,
    const float* __restrict__ distA, const float* __restrict__ rankA,
    const float* __restrict__ cntA,  const float* __restrict__ dist2,
    const float* __restrict__ rank2, const float* __restrict__ cnt2,
    float* __restrict__ out)
{
    const int tid = threadIdx.x;
    float sper = 0.f, sval = 0.f;
    for (int i = tid; i < F; i += TPB) {
        float d = dist2[i], rk = rank2[i], c = cnt2[i];
        for (int s = 0; s < S; ++s) {
            d  += distA[s * F + i];
            rk += rankA[s * F + i];
            c  += cntA[s * F + i];
        }
        if (c > 0.f) {
            sper += (d * APE_LN2) * ious[i] / rk;
            sval += 1.f;
        }
    }
    __shared__ float rp[4], rv[4];
    const int lane = tid & 63, wid = tid >> 6;
    for (int off = 32; off > 0; off >>= 1) {
        sper += __shfl_down(sper, off);
        sval += __shfl_down(sval, off);
    }
    if (lane == 0) { rp[wid] = sper; rv[wid] = sval; }
    __syncthreads();
    if (tid == 0) {
        float p = rp[0] + rp[1] + rp[2] + rp[3];
        float v = rv[0] + rv[1] + rv[2] + rv[3];
        out[0] = p / fmaxf(v, 1.f) / APE_LAMB;
    }
}

extern "C" void kernel_launch(void* const* d_in, const int* in_sizes, int n_in,
                              void* d_out, int out_size, void* d_ws, size_t ws_size,
                              hipStream_t stream) {
    const float* logits = (const float*)d_in[0];
    // d_in[1] = targets (unused); d_in[3] = num_fg (value == F == len(ious))
    const float* ious   = (const float*)d_in[2];
    const int N = in_sizes[0];
    const int F = in_sizes[2];
    const int M = N - F;

    float* ws    = (float*)d_ws;
    float* distA = ws;                        // [S][F]
    float* rankA = distA + S_CHUNKS * F;      // [S][F]
    float* cntA  = rankA + S_CHUNKS * F;      // [S][F]
    float* dist2 = cntA  + S_CHUNKS * F;      // [F]
    float* rank2 = dist2 + F;                 // [F]
    float* cnt2  = rank2 + F;                 // [F]

    const int G = (F + ROWS_A - 1) / ROWS_A;
    int chunkLen = ((M + S_CHUNKS - 1) / S_CHUNKS + 3) & ~3;
    if (chunkLen < 4) chunkLen = 4;

    dim3 gridA(G, S_CHUNKS);
    ape_bg_kernel<<<gridA, TPB, 0, stream>>>(logits, F, M, chunkLen, distA, rankA, cntA);
    ape_fg_kernel<<<(F + ROWS_B - 1) / ROWS_B, TPB, 0, stream>>>(logits, ious, F,
                                                                 dist2, rank2, cnt2);
    ape_final_kernel<<<1, TPB, 0, stream>>>(ious, F, S_CHUNKS, distA, rankA, cntA,
                                            dist2, rank2, cnt2, (float*)d_out);
}

// Round 2
// 90.421 us; speedup vs baseline: 1.0701x; 1.0701x over previous
//
#include <hip/hip_runtime.h>
#include <hip/hip_bf16.h>

// APELoss: F fg logits vs M bg logits pairwise + F x F fg part.
// mask = b > f + TH (TH=-1); rel_bg is implied by mask (p_min <= fg[i]).
// Log2 domain: dl = (b-f)*LAMB*log2e; clamp dl -> -inf when unmasked. Then
//   u = 2^dl, o = 1+u:
//   sigmoid(d)      = 1 - rcp(o)      (rank = n_proc - sum rcp(o))
//   softplus(d)/ln2 = log2(o)
// Unmasked: u=0, o=1 -> rcp=1 (cancels via n_proc), log2=0.  3 trans + 6 VALU/pair.
// count>0 is recovered as (max_bg > fg[i]+TH) || fg_pos_count>0 -- no cnt accum.

#define APE_LAMB 4.0f
#define APE_KC   5.770780163555856f   // LAMB * log2(e); mask: dl > -APE_KC
#define APE_LN2  0.6931471805599453f
#define NINF     (-__builtin_inff())

__device__ __forceinline__ float exp2g(float x) { return __builtin_amdgcn_exp2f(x); }
__device__ __forceinline__ float log2g(float x) { return __builtin_amdgcn_logf(x); }
__device__ __forceinline__ float rcpg(float x)  { return __builtin_amdgcn_rcpf(x); }

constexpr int S_MAX  = 21;   // bg chunks; 150528 = 21 * 7168, 7168 = 7*256*4
constexpr int ROWS_A = 8;    // fg rows per block in bg kernel
constexpr int ROWS_B = 4;    // fg rows per block in fg-fg kernel
constexpr int TPB    = 256;

// ---------------- bg kernel: rank/dist partials + bg max --------------------
__global__ __launch_bounds__(TPB) void ape_bg_kernel(
    const float* __restrict__ logits, int F, int M, int chunkLen, int G,
    float* __restrict__ distA, float* __restrict__ rankA, float* __restrict__ bmaxA)
{
    const int rg  = blockIdx.x;
    const int s   = blockIdx.y;
    const int tid = threadIdx.x;
    const float* bg = logits + F;
    const int i0 = rg * ROWS_A;

    float fgl[ROWS_A];
#pragma unroll
    for (int r = 0; r < ROWS_A; ++r) {
        int i = i0 + r;
        fgl[r] = (i < F) ? logits[i] * APE_KC : __builtin_inff();
    }

    float dist[ROWS_A], rk2[ROWS_A];
#pragma unroll
    for (int r = 0; r < ROWS_A; ++r) { dist[r] = 0.f; rk2[r] = 0.f; }

    const int start = s * chunkLen;
    const int end   = min(start + chunkLen, M);
    float bmax = NINF;
    int nproc = 0;

    for (int j = start + tid * 4; j < end; j += TPB * 4) {
        float v[4];
        if (j + 4 <= end) {
            float4 q = *reinterpret_cast<const float4*>(bg + j);
            v[0] = q.x; v[1] = q.y; v[2] = q.z; v[3] = q.w;
        } else {
#pragma unroll
            for (int k = 0; k < 4; ++k)
                v[k] = (j + k < end) ? bg[j + k] : NINF;   // -inf pad self-cancels
        }
        nproc += 4;
#pragma unroll
        for (int k = 0; k < 4; ++k) {
            bmax = fmaxf(bmax, v[k]);
            float bgl = v[k] * APE_KC;
#pragma unroll
            for (int r = 0; r < ROWS_A; ++r) {
                float dl = bgl - fgl[r];
                float dm = (dl > -APE_KC) ? dl : NINF;
                float u  = exp2g(dm);
                float o  = 1.0f + u;
                rk2[r]  += rcpg(o);
                dist[r] += log2g(o);
            }
        }
    }

    float rankp[ROWS_A];
#pragma unroll
    for (int r = 0; r < ROWS_A; ++r) rankp[r] = (float)nproc - rk2[r];

    __shared__ float red[4][ROWS_A * 2];
    __shared__ float redm[4];
    const int lane = tid & 63, wid = tid >> 6;
#pragma unroll
    for (int r = 0; r < ROWS_A; ++r) {
        float d = dist[r], rk = rankp[r];
        for (int off = 32; off > 0; off >>= 1) {
            d  += __shfl_down(d, off);
            rk += __shfl_down(rk, off);
        }
        if (lane == 0) { red[wid][r*2+0] = d; red[wid][r*2+1] = rk; }
    }
    {
        float m = bmax;
        for (int off = 32; off > 0; off >>= 1) m = fmaxf(m, __shfl_down(m, off));
        if (lane == 0) redm[wid] = m;
    }
    __syncthreads();
    if (tid < ROWS_A * 2) {
        float sum = red[0][tid] + red[1][tid] + red[2][tid] + red[3][tid];
        int r = tid / 2, q = tid % 2;
        int i = i0 + r;
        if (i < F) {
            int idx = s * F + i;
            if (q == 0) distA[idx] = sum;
            else        rankA[idx] = sum;
        }
    }
    if (tid == 0)
        bmaxA[s * G + rg] = fmaxf(fmaxf(redm[0], redm[1]), fmaxf(redm[2], redm[3]));
}

// ---------------- fg-fg kernel: pos/tp contributions ------------------------
__global__ __launch_bounds__(TPB) void ape_fg_kernel(
    const float* __restrict__ logits, const float* __restrict__ ious, int F,
    float* __restrict__ dist2, float* __restrict__ rank2, float* __restrict__ cnt2)
{
    const int i0  = blockIdx.x * ROWS_B;
    const int tid = threadIdx.x;

    float fgl[ROWS_B], ioui[ROWS_B];
#pragma unroll
    for (int r = 0; r < ROWS_B; ++r) {
        int i = i0 + r;
        fgl[r]  = (i < F) ? logits[i] * APE_KC : __builtin_inff();
        ioui[r] = (i < F) ? ious[i] : 0.f;
    }

    float dist[ROWS_B], rank[ROWS_B], cnt[ROWS_B];
#pragma unroll
    for (int r = 0; r < ROWS_B; ++r) { dist[r] = 0.f; rank[r] = 0.f; cnt[r] = 0.f; }

    for (int j = tid; j < F; j += TPB) {
        float fjl  = logits[j] * APE_KC;
        float iouj = ious[j];
#pragma unroll
        for (int r = 0; r < ROWS_B; ++r) {
            float dl = fjl - fgl[r];
            bool above = dl > -APE_KC;
            float dm = above ? dl : NINF;
            float u  = exp2g(dm);
            float o  = 1.0f + u;
            float sig = 1.0f - rcpg(o);
            float spl = log2g(o);          // 0 when !above
            bool pos = iouj < ioui[r];
            rank[r] += sig;
            dist[r] += pos ? spl : 0.f;
            cnt[r]  += (above && pos) ? 1.f : 0.f;
        }
    }

    __shared__ float red[4][ROWS_B * 3];
    const int lane = tid & 63, wid = tid >> 6;
#pragma unroll
    for (int r = 0; r < ROWS_B; ++r) {
        float d = dist[r], rk = rank[r], c = cnt[r];
        for (int off = 32; off > 0; off >>= 1) {
            d  += __shfl_down(d, off);
            rk += __shfl_down(rk, off);
            c  += __shfl_down(c, off);
        }
        if (lane == 0) { red[wid][r*3+0] = d; red[wid][r*3+1] = rk; red[wid][r*3+2] = c; }
    }
    __syncthreads();
    if (tid < ROWS_B * 3) {
        float sum = red[0][tid] + red[1][tid] + red[2][tid] + red[3][tid];
        int r = tid / 3, q = tid % 3;
        int i = i0 + r;
        if (i < F) {
            if      (q == 0) dist2[i] = sum;
            else if (q == 1) rank2[i] = sum;
            else             cnt2[i]  = sum;
        }
    }
}

// ---------------- final: combine partials, per-row loss, scalar out ---------
__global__ __launch_bounds__(TPB) void ape_final_kernel(
    const float* __restrict__ logits, const float* __restrict__ ious, int F, int S, int G,
    const float* __restrict__ distA, const float* __restrict__ rankA,
    const float* __restrict__ bmaxA, const float* __restrict__ dist2,
    const float* __restrict__ rank2, const float* __restrict__ cnt2,
    float* __restrict__ out)
{
    const int tid = threadIdx.x;
    const int lane = tid & 63, wid = tid >> 6;
    __shared__ float rm[4];
    __shared__ float gmax_s;

    // global bg max
    float m = NINF;
    for (int t = tid; t < S * G; t += TPB) m = fmaxf(m, bmaxA[t]);
    for (int off = 32; off > 0; off >>= 1) m = fmaxf(m, __shfl_down(m, off));
    if (lane == 0) rm[wid] = m;
    __syncthreads();
    if (tid == 0) gmax_s = fmaxf(fmaxf(rm[0], rm[1]), fmaxf(rm[2], rm[3]));
    __syncthreads();
    const float gmax = gmax_s;

    float sper = 0.f, sval = 0.f;
    for (int i = tid; i < F; i += TPB) {
        float d = dist2[i], rk = rank2[i];
        for (int s = 0; s < S; ++s) {
            d  += distA[s * F + i];
            rk += rankA[s * F + i];
        }
        bool valid = (gmax > logits[i] - 1.0f) || (cnt2[i] > 0.f);
        if (valid) {
            sper += (d * APE_LN2) * ious[i] / rk;
            sval += 1.f;
        }
    }
    __shared__ float rp[4], rv[4];
    for (int off = 32; off > 0; off >>= 1) {
        sper += __shfl_down(sper, off);
        sval += __shfl_down(sval, off);
    }
    if (lane == 0) { rp[wid] = sper; rv[wid] = sval; }
    __syncthreads();
    if (tid == 0) {
        float p = rp[0] + rp[1] + rp[2] + rp[3];
        float v = rv[0] + rv[1] + rv[2] + rv[3];
        out[0] = p / fmaxf(v, 1.f) / APE_LAMB;
    }
}

extern "C" void kernel_launch(void* const* d_in, const int* in_sizes, int n_in,
                              void* d_out, int out_size, void* d_ws, size_t ws_size,
                              hipStream_t stream) {
    const float* logits = (const float*)d_in[0];
    const float* ious   = (const float*)d_in[2];
    const int N = in_sizes[0];
    const int F = in_sizes[2];
    const int M = N - F;

    const int G = (F + ROWS_A - 1) / ROWS_A;

    // pick S to fit workspace: S*(2F + G) + 3F floats needed
    size_t avail = ws_size / sizeof(float);
    long per_s = 2L * F + G;
    long budget = (long)avail - 3L * F;
    int S = (budget > per_s) ? (int)(budget / per_s) : 1;
    if (S > S_MAX) S = S_MAX;
    if (S < 1) S = 1;

    float* ws    = (float*)d_ws;
    float* distA = ws;                    // [S][F]
    float* rankA = distA + (size_t)S * F; // [S][F]
    float* bmaxA = rankA + (size_t)S * F; // [S][G]
    float* dist2 = bmaxA + (size_t)S * G; // [F]
    float* rank2 = dist2 + F;             // [F]
    float* cnt2  = rank2 + F;             // [F]

    int chunkLen = ((M + S - 1) / S + 3) & ~3;
    if (chunkLen < 4) chunkLen = 4;

    dim3 gridA(G, S);
    ape_bg_kernel<<<gridA, TPB, 0, stream>>>(logits, F, M, chunkLen, G,
                                             distA, rankA, bmaxA);
    ape_fg_kernel<<<(F + ROWS_B - 1) / ROWS_B, TPB, 0, stream>>>(logits, ious, F,
                                                                 dist2, rank2, cnt2);
    ape_final_kernel<<<1, TPB, 0, stream>>>(logits, ious, F, S, G, distA, rankA,
                                            bmaxA, dist2, rank2, cnt2, (float*)d_out);
}

// Round 3
// 24.081 us; speedup vs baseline: 4.0180x; 3.7548x over previous
//
#include <hip/hip_runtime.h>
#include <hip/hip_bf16.h>

// APELoss via moment-corrected histogram.
// rank_i = sum_j sigmoid(LAMB*(b_j - f_i)) over masked (b > f_i - 1)
// dist_i = sum_j softplus(LAMB*(b_j - f_i)) over masked
// Bin bg (B=2048, delta=0.005): integer count + fixed-point first moment
// m1 = sum(v - c_bin)  (deterministic integer atomics). Per (row,bin):
//   f(c)*cnt + f'(c)*m1     (first-order Taylor; curvature error ~1e-6 rel)
// Log2 domain per eval: dl = KC*(c - f); mask dl > -KC else -inf.
//   u = 2^dl, o = 1+u, rr = rcp(o), s = 1-rr = sigmoid, lg = log2(o) = softplus/ln2
//   d(sigmoid)/dv = LAMB*s*rr ; d(lg)/dv = KC*s
// fg x fg part (1M pairs) exact pairwise. Validity via exact bg max.

#define APE_LAMB 4.0f
#define APE_KC   5.770780163555856f   // LAMB * log2(e)
#define APE_LN2  0.6931471805599453f
#define NINF     (-__builtin_inff())

__device__ __forceinline__ float exp2g(float x) { return __builtin_amdgcn_exp2f(x); }
__device__ __forceinline__ float log2g(float x) { return __builtin_amdgcn_logf(x); }
__device__ __forceinline__ float rcpg(float x)  { return __builtin_amdgcn_rcpf(x); }

constexpr int   B_BINS  = 2048;
constexpr int   NB      = 16;     // build blocks
constexpr int   TPB     = 256;
constexpr float BIN_LO  = -5.12f;
constexpr float BIN_DL  = 0.005f;          // delta
constexpr float BIN_INV = 200.0f;          // 1/delta
constexpr float M1SCALE = 268435456.0f;    // 2^28 fixed point for m1
constexpr float M1INV   = 3.725290298461914e-09f;  // 2^-28
constexpr int   ROWS_E  = 4;      // fg rows per eval block
constexpr int   ROWS_B  = 4;      // fg rows per fg-fg block

// ---------------- build: deterministic integer histogram + exact bg max ----
__global__ __launch_bounds__(TPB) void ape_build(
    const float* __restrict__ logits, int F, int M,
    int* __restrict__ gCnt, int* __restrict__ gM1, float* __restrict__ bmaxA)
{
    __shared__ int hc[B_BINS];
    __shared__ int hm[B_BINS];
    const int tid = threadIdx.x;
    for (int b = tid; b < B_BINS; b += TPB) { hc[b] = 0; hm[b] = 0; }
    __syncthreads();

    const float* bg = logits + F;
    float bmax = NINF;
    const int stride = gridDim.x * TPB * 4;
    for (int j = ((int)blockIdx.x * TPB + tid) * 4; j < M; j += stride) {
        float v[4];
        if (j + 4 <= M) {
            float4 q = *reinterpret_cast<const float4*>(bg + j);
            v[0] = q.x; v[1] = q.y; v[2] = q.z; v[3] = q.w;
        } else {
#pragma unroll
            for (int k = 0; k < 4; ++k) v[k] = (j + k < M) ? bg[j + k] : NINF;
        }
#pragma unroll
        for (int k = 0; k < 4; ++k) {
            if (j + k >= M) continue;
            float x = v[k];
            bmax = fmaxf(bmax, x);
            int b = (int)((x - BIN_LO) * BIN_INV);
            b = min(max(b, 0), B_BINS - 1);
            float c = fmaf((float)b, BIN_DL, BIN_LO + 0.5f * BIN_DL);
            int q = __float2int_rn((x - c) * M1SCALE);
            atomicAdd(&hc[b], 1);
            atomicAdd(&hm[b], q);
        }
    }
    __syncthreads();
    for (int b = tid; b < B_BINS; b += TPB) {
        int c = hc[b];
        if (c) { atomicAdd(&gCnt[b], c); atomicAdd(&gM1[b], hm[b]); }
    }
    __shared__ float rm[4];
    const int lane = tid & 63, wid = tid >> 6;
    for (int off = 32; off > 0; off >>= 1) bmax = fmaxf(bmax, __shfl_down(bmax, off));
    if (lane == 0) rm[wid] = bmax;
    __syncthreads();
    if (tid == 0)
        bmaxA[blockIdx.x] = fmaxf(fmaxf(rm[0], rm[1]), fmaxf(rm[2], rm[3]));
}

// ---------------- eval: bg-histogram rows (blocks < EB) + fg-fg (rest) -----
__global__ __launch_bounds__(TPB) void ape_eval(
    const float* __restrict__ logits, const float* __restrict__ ious, int F, int EB,
    const int* __restrict__ gCnt, const int* __restrict__ gM1,
    float* __restrict__ rankB, float* __restrict__ distB,
    float* __restrict__ dist2, float* __restrict__ rank2, float* __restrict__ cnt2)
{
    const int tid  = threadIdx.x;
    const int lane = tid & 63, wid = tid >> 6;

    if ((int)blockIdx.x < EB) {
        // ---- bg part via histogram ----
        __shared__ float2 h[B_BINS];   // (count, m1 in logit units)
        for (int b = tid; b < B_BINS; b += TPB)
            h[b] = make_float2((float)gCnt[b], (float)gM1[b] * M1INV);

        const int i0 = (int)blockIdx.x * ROWS_E;
        float fKC[ROWS_E];
#pragma unroll
        for (int r = 0; r < ROWS_E; ++r) {
            int i = i0 + r;
            fKC[r] = (i < F) ? logits[i] * APE_KC : __builtin_inff();
        }
        __syncthreads();

        float rk[ROWS_E], dt[ROWS_E];
#pragma unroll
        for (int r = 0; r < ROWS_E; ++r) { rk[r] = 0.f; dt[r] = 0.f; }

        for (int it = 0; it < B_BINS; it += TPB) {
            const int b = it + tid;
            float2 cm = h[b];
            float cKC  = fmaf((float)b, BIN_DL * APE_KC,
                              (BIN_LO + 0.5f * BIN_DL) * APE_KC);
            float m1x4 = cm.y * APE_LAMB;
            float m1kc = cm.y * APE_KC;
#pragma unroll
            for (int r = 0; r < ROWS_E; ++r) {
                float dl = cKC - fKC[r];
                float dm = (dl > -APE_KC) ? dl : NINF;
                float u  = exp2g(dm);
                float o  = 1.0f + u;
                float rr = rcpg(o);
                float lg = log2g(o);
                float s  = 1.0f - rr;
                rk[r] = fmaf(cm.x, s,  rk[r]);
                rk[r] = fmaf(m1x4, s * rr, rk[r]);
                dt[r] = fmaf(cm.x, lg, dt[r]);
                dt[r] = fmaf(m1kc, s,  dt[r]);
            }
        }

        __shared__ float red[4][ROWS_E * 2];
#pragma unroll
        for (int r = 0; r < ROWS_E; ++r) {
            float a = rk[r], d = dt[r];
            for (int off = 32; off > 0; off >>= 1) {
                a += __shfl_down(a, off);
                d += __shfl_down(d, off);
            }
            if (lane == 0) { red[wid][r*2+0] = a; red[wid][r*2+1] = d; }
        }
        __syncthreads();
        if (tid < ROWS_E * 2) {
            float sum = red[0][tid] + red[1][tid] + red[2][tid] + red[3][tid];
            int r = tid >> 1, q = tid & 1;
            int i = i0 + r;
            if (i < F) {
                if (q == 0) rankB[i] = sum;
                else        distB[i] = sum;
            }
        }
    } else {
        // ---- fg-fg part (exact pairwise) ----
        const int i0 = ((int)blockIdx.x - EB) * ROWS_B;
        float fgl[ROWS_B], ioui[ROWS_B];
#pragma unroll
        for (int r = 0; r < ROWS_B; ++r) {
            int i = i0 + r;
            fgl[r]  = (i < F) ? logits[i] * APE_KC : __builtin_inff();
            ioui[r] = (i < F) ? ious[i] : 0.f;
        }
        float dist[ROWS_B], rank[ROWS_B], cnt[ROWS_B];
#pragma unroll
        for (int r = 0; r < ROWS_B; ++r) { dist[r]=0.f; rank[r]=0.f; cnt[r]=0.f; }

        for (int j = tid; j < F; j += TPB) {
            float fjl  = logits[j] * APE_KC;
            float iouj = ious[j];
#pragma unroll
            for (int r = 0; r < ROWS_B; ++r) {
                float dl = fjl - fgl[r];
                bool above = dl > -APE_KC;
                float dm = above ? dl : NINF;
                float u  = exp2g(dm);
                float o  = 1.0f + u;
                float sig = 1.0f - rcpg(o);
                float spl = log2g(o);
                bool pos = iouj < ioui[r];
                rank[r] += sig;
                dist[r] += pos ? spl : 0.f;
                cnt[r]  += (above && pos) ? 1.f : 0.f;
            }
        }
        __shared__ float redf[4][ROWS_B * 3];
#pragma unroll
        for (int r = 0; r < ROWS_B; ++r) {
            float d = dist[r], a = rank[r], c = cnt[r];
            for (int off = 32; off > 0; off >>= 1) {
                d += __shfl_down(d, off);
                a += __shfl_down(a, off);
                c += __shfl_down(c, off);
            }
            if (lane == 0) { redf[wid][r*3+0]=d; redf[wid][r*3+1]=a; redf[wid][r*3+2]=c; }
        }
        __syncthreads();
        if (tid < ROWS_B * 3) {
            float sum = redf[0][tid] + redf[1][tid] + redf[2][tid] + redf[3][tid];
            int r = tid / 3, q = tid % 3;
            int i = i0 + r;
            if (i < F) {
                if      (q == 0) dist2[i] = sum;
                else if (q == 1) rank2[i] = sum;
                else             cnt2[i]  = sum;
            }
        }
    }
}

// ---------------- final: combine, per-row loss, scalar out ------------------
__global__ __launch_bounds__(TPB) void ape_final(
    const float* __restrict__ logits, const float* __restrict__ ious, int F,
    const float* __restrict__ rankB, const float* __restrict__ distB,
    const float* __restrict__ dist2, const float* __restrict__ rank2,
    const float* __restrict__ cnt2,  const float* __restrict__ bmaxA,
    float* __restrict__ out)
{
    const int tid = threadIdx.x;
    const int lane = tid & 63, wid = tid >> 6;
    __shared__ float gms;
    if (tid == 0) {
        float m = NINF;
        for (int k = 0; k < NB; ++k) m = fmaxf(m, bmaxA[k]);
        gms = m;
    }
    __syncthreads();
    const float gmax = gms;

    float sper = 0.f, sval = 0.f;
    for (int i = tid; i < F; i += TPB) {
        float rkv = rankB[i] + rank2[i];
        float dtv = (distB[i] + dist2[i]) * APE_LN2;
        bool valid = (gmax > logits[i] - 1.0f) || (cnt2[i] > 0.f);
        if (valid) {
            sper += dtv * ious[i] / rkv;
            sval += 1.f;
        }
    }
    __shared__ float rp[4], rv[4];
    for (int off = 32; off > 0; off >>= 1) {
        sper += __shfl_down(sper, off);
        sval += __shfl_down(sval, off);
    }
    if (lane == 0) { rp[wid] = sper; rv[wid] = sval; }
    __syncthreads();
    if (tid == 0) {
        float p = rp[0] + rp[1] + rp[2] + rp[3];
        float v = rv[0] + rv[1] + rv[2] + rv[3];
        out[0] = p / fmaxf(v, 1.f) / APE_LAMB;
    }
}

extern "C" void kernel_launch(void* const* d_in, const int* in_sizes, int n_in,
                              void* d_out, int out_size, void* d_ws, size_t ws_size,
                              hipStream_t stream) {
    const float* logits = (const float*)d_in[0];
    const float* ious   = (const float*)d_in[2];
    const int N = in_sizes[0];
    const int F = in_sizes[2];
    const int M = N - F;

    int*   gCnt  = (int*)d_ws;            // [B_BINS]
    int*   gM1   = gCnt + B_BINS;         // [B_BINS]
    float* bmaxA = (float*)(gM1 + B_BINS);// [NB]
    float* rankB = bmaxA + NB;            // [F]
    float* distB = rankB + F;             // [F]
    float* dist2 = distB + F;             // [F]
    float* rank2 = dist2 + F;             // [F]
    float* cnt2  = rank2 + F;             // [F]

    hipMemsetAsync(gCnt, 0, 2 * B_BINS * sizeof(int), stream);
    ape_build<<<NB, TPB, 0, stream>>>(logits, F, M, gCnt, gM1, bmaxA);

    const int EB = (F + ROWS_E - 1) / ROWS_E;
    const int FB = (F + ROWS_B - 1) / ROWS_B;
    ape_eval<<<EB + FB, TPB, 0, stream>>>(logits, ious, F, EB, gCnt, gM1,
                                          rankB, distB, dist2, rank2, cnt2);
    ape_final<<<1, TPB, 0, stream>>>(logits, ious, F, rankB, distB, dist2, rank2,
                                     cnt2, bmaxA, (float*)d_out);
}